// Round 1
// baseline (1463.541 us; speedup 1.0000x reference)
//
#include <hip/hip_runtime.h>

// LSTMAutoRegressive: B=1024, T=1024, H1=64, H2=32, n_in=n_out=1.
// Design: 64 workgroups x 1024 threads; wg bg owns batches [16bg,16bg+16).
// MFMA 16x16x32 bf16, swapped operands: A = weights (M=16 gate-rows, perm
// [i,f,g,o]x4units), B = h (N=16 batch). bf16 hi/lo split for ~fp32 accuracy.
// Weights live in VGPRs (per-wave constant A-frags). LDS: double-buffered h.
// One __syncthreads per timestep.

using short8 = __attribute__((ext_vector_type(8))) short;   // 8 bf16
using f32x4  = __attribute__((ext_vector_type(4))) float;   // C/D frag

#define MFMA16(A,B,C) __builtin_amdgcn_mfma_f32_16x16x32_bf16((A),(B),(C),0,0,0)

__device__ __forceinline__ unsigned short bf_hi_bits(float f){
    union { float f; unsigned u; } v; v.f = f;
    return (unsigned short)(v.u >> 16);          // truncation to bf16
}
__device__ __forceinline__ float hi_masked(float f){
    union { float f; unsigned u; } v; v.f = f;
    v.u &= 0xFFFF0000u; return v.f;              // exact bf16-representable part
}
__device__ __forceinline__ float sigf(float x){
    float e = __expf(-x);
    return __fdividef(1.0f, 1.0f + e);
}
__device__ __forceinline__ float tanhf_fast(float x){
    float e = __expf(-2.0f * x);
    return __fdividef(1.0f - e, 1.0f + e);
}

__global__ __launch_bounds__(1024, 4)
void lstm_ar_kernel(const float* __restrict__ x_in,
                    const float* __restrict__ dly_in,
                    const float* __restrict__ W_ih1, const float* __restrict__ W_hh1,
                    const float* __restrict__ b_ih1, const float* __restrict__ b_hh1,
                    const float* __restrict__ W_ih2, const float* __restrict__ W_hh2,
                    const float* __restrict__ b_ih2, const float* __restrict__ b_hh2,
                    const float* __restrict__ W_out, const float* __restrict__ b_out,
                    float* __restrict__ out)
{
    // h buffers: [parity][batch 16][k 200], k-map (bf16 elements):
    //   [0,64)   h1_hi   [64,128) h1_lo   [128,160) h2_hi   [160,192) h2_lo
    // row stride 200 els = 400B (16B aligned, bank-spread 4b+k/2 -> 2-way floor)
    __shared__ __align__(16) unsigned short hlds[2][16][200];

    const int tid = threadIdx.x;
    const int w   = tid >> 6;     // wave 0..15
    const int l   = tid & 63;
    const int lb  = l & 15;       // A-row index / batch column (role per phase)
    const int lq  = l >> 4;       // quarter-wave
    const int bg  = blockIdx.x;
    const int T   = 1024;
    const int bglob = bg * 16 + lb;

    // zero both h buffers (h[-1] = 0)
    for (int i = tid; i < 2 * 16 * 200; i += 1024)
        ((unsigned short*)hlds)[i] = 0;

    // ---- per-lane constant weights ----
    // A-row rho=lb of tile w: type=rho&3 (i,f,g,o), unit = 4w + (rho>>2)
    const int rho = lb;
    const int ty  = rho & 3;
    const int du  = rho >> 2;

    // Layer-1 A-frags: gate g1 = ty*64 + (4w+du), k window = 32s + lq*8 + i
    const int g1 = ty * 64 + (4 * w + du);
    short8 w1hi[2], w1lo[2];
    for (int s = 0; s < 2; ++s)
        for (int i = 0; i < 8; ++i) {
            int j = 32 * s + lq * 8 + i;
            float wv  = W_hh1[g1 * 64 + j];
            float whi = hi_masked(wv);
            w1hi[s][i] = (short)bf_hi_bits(wv);
            w1lo[s][i] = (short)bf_hi_bits(wv - whi);
        }

    // ACT-1 per-lane: unit1 = 4w+lq, batch lb; gates r*64+unit1
    const int unit1 = 4 * w + lq;
    float bias1[4], wxx[4], wxd[4];
    for (int r = 0; r < 4; ++r) {
        int g = r * 64 + unit1;
        bias1[r] = b_ih1[g] + b_hh1[g];
        wxx[r]   = W_ih1[g * 2 + 0];
        wxd[r]   = W_ih1[g * 2 + 1];
    }

    // Layer-2 (waves 0..7): g2 = ty*32 + (4w+du)
    short8 w2ihhi[2], w2ihlo[2], w2hhhi, w2hhlo;
    float bias2[4] = {0.f, 0.f, 0.f, 0.f};
    const int unit2 = 4 * w + lq;   // valid for w<8
    if (w < 8) {
        int g2 = ty * 32 + (4 * w + du);
        for (int s = 0; s < 2; ++s)
            for (int i = 0; i < 8; ++i) {
                int j = 32 * s + lq * 8 + i;
                float wv  = W_ih2[g2 * 64 + j];
                float whi = hi_masked(wv);
                w2ihhi[s][i] = (short)bf_hi_bits(wv);
                w2ihlo[s][i] = (short)bf_hi_bits(wv - whi);
            }
        for (int i = 0; i < 8; ++i) {
            int j = lq * 8 + i;
            float wv  = W_hh2[g2 * 32 + j];
            float whi = hi_masked(wv);
            w2hhhi[i] = (short)bf_hi_bits(wv);
            w2hhlo[i] = (short)bf_hi_bits(wv - whi);
        }
        for (int r = 0; r < 4; ++r) {
            int g = r * 32 + unit2;
            bias2[r] = b_ih2[g] + b_hh2[g];
        }
    }

    // y tile (wave 8): A row0 = W_out, rows 1..15 = 0
    short8 wouthi, woutlo;
    if (w == 8) {
        for (int i = 0; i < 8; ++i) {
            int j = lq * 8 + i;
            float wv  = (rho == 0) ? W_out[j] : 0.0f;
            float whi = hi_masked(wv);
            wouthi[i] = (short)bf_hi_bits(wv);
            woutlo[i] = (short)bf_hi_bits(wv - whi);
        }
    }
    const float bout = b_out[0];

    float c1 = 0.0f, c2 = 0.0f;
    const float* xp = x_in  + bglob * T;
    const float* dp = dly_in + bglob * T;
    float*       op = out   + bglob * T;

    __syncthreads();

    #pragma unroll 2
    for (int t = 0; t < T; ++t) {
        const int p  = t & 1;
        const int pp = p ^ 1;

        // ---------- Phase A: layer-1 MFMA (reads h1[t-1] from hlds[pp]) ----------
        float xv = xp[t];
        float dv = dp[t];
        const unsigned short* rb = &hlds[pp][lb][0];
        short8 hh0 = *(const short8*)(rb + 0  + lq * 8);
        short8 hh1 = *(const short8*)(rb + 32 + lq * 8);
        short8 hl0 = *(const short8*)(rb + 64 + lq * 8);
        short8 hl1 = *(const short8*)(rb + 96 + lq * 8);
        f32x4 acc = {0.f, 0.f, 0.f, 0.f};
        acc = MFMA16(w1hi[0], hh0, acc);
        acc = MFMA16(w1hi[1], hh1, acc);
        acc = MFMA16(w1hi[0], hl0, acc);
        acc = MFMA16(w1hi[1], hl1, acc);
        acc = MFMA16(w1lo[0], hh0, acc);
        acc = MFMA16(w1lo[1], hh1, acc);

        // ---------- ACT-1 (lane-local: unit1, batch lb) ----------
        float gi = acc[0] + bias1[0] + wxx[0] * xv + wxd[0] * dv;
        float gf = acc[1] + bias1[1] + wxx[1] * xv + wxd[1] * dv;
        float gg = acc[2] + bias1[2] + wxx[2] * xv + wxd[2] * dv;
        float go = acc[3] + bias1[3] + wxx[3] * xv + wxd[3] * dv;
        float ig = sigf(gi), fg = sigf(gf), gt = tanhf_fast(gg), og = sigf(go);
        c1 = fg * c1 + ig * gt;
        float h1 = og * tanhf_fast(c1);
        unsigned short h1hib = bf_hi_bits(h1);
        float h1hif = hi_masked(h1);
        unsigned short h1lob = bf_hi_bits(h1 - h1hif);
        hlds[p][lb][unit1]      = h1hib;
        hlds[p][lb][64 + unit1] = h1lob;

        __syncthreads();   // the only barrier per step

        // ---------- Phase B: layer-2 MFMA + y ----------
        if (w < 8) {
            const unsigned short* rb1 = &hlds[p][lb][0];   // h1[t]
            const unsigned short* rb2 = &hlds[pp][lb][0];  // h2[t-1]
            short8 a0 = *(const short8*)(rb1 + 0   + lq * 8);
            short8 a1 = *(const short8*)(rb1 + 32  + lq * 8);
            short8 a2 = *(const short8*)(rb1 + 64  + lq * 8);
            short8 a3 = *(const short8*)(rb1 + 96  + lq * 8);
            short8 b0 = *(const short8*)(rb2 + 128 + lq * 8);
            short8 b1 = *(const short8*)(rb2 + 160 + lq * 8);
            f32x4 q = {0.f, 0.f, 0.f, 0.f};
            q = MFMA16(w2ihhi[0], a0, q);
            q = MFMA16(w2ihhi[1], a1, q);
            q = MFMA16(w2ihhi[0], a2, q);
            q = MFMA16(w2ihhi[1], a3, q);
            q = MFMA16(w2ihlo[0], a0, q);
            q = MFMA16(w2ihlo[1], a1, q);
            q = MFMA16(w2hhhi,    b0, q);
            q = MFMA16(w2hhhi,    b1, q);
            q = MFMA16(w2hhlo,    b0, q);
            // ACT-2 (lane-local: unit2, batch lb)
            float g2i = q[0] + bias2[0];
            float g2f = q[1] + bias2[1];
            float g2g = q[2] + bias2[2];
            float g2o = q[3] + bias2[3];
            float i2 = sigf(g2i), f2 = sigf(g2f), gt2 = tanhf_fast(g2g), o2 = sigf(g2o);
            c2 = f2 * c2 + i2 * gt2;
            float h2 = o2 * tanhf_fast(c2);
            unsigned short hb = bf_hi_bits(h2);
            float hf = hi_masked(h2);
            unsigned short lo = bf_hi_bits(h2 - hf);
            hlds[p][lb][128 + unit2] = hb;
            hlds[p][lb][160 + unit2] = lo;
        } else if (w == 8) {
            // y[t-1] = h2[t-1] . W_out + b_out  (h2[t-1] in hlds[pp])
            const unsigned short* rb2 = &hlds[pp][lb][0];
            short8 b0 = *(const short8*)(rb2 + 128 + lq * 8);
            short8 b1 = *(const short8*)(rb2 + 160 + lq * 8);
            f32x4 q = {0.f, 0.f, 0.f, 0.f};
            q = MFMA16(wouthi, b0, q);
            q = MFMA16(wouthi, b1, q);
            q = MFMA16(woutlo, b0, q);
            if (lq == 0 && t > 0) op[t - 1] = q[0] + bout;
        }
        // no second barrier: parity + B1 ordering makes it safe (see analysis)
    }

    __syncthreads();
    if (w == 8) {
        // emit y[1023] from h2[1023] (buffer parity 1023&1 = 1)
        const unsigned short* rb2 = &hlds[1][lb][0];
        short8 b0 = *(const short8*)(rb2 + 128 + lq * 8);
        short8 b1 = *(const short8*)(rb2 + 160 + lq * 8);
        f32x4 q = {0.f, 0.f, 0.f, 0.f};
        q = MFMA16(wouthi, b0, q);
        q = MFMA16(wouthi, b1, q);
        q = MFMA16(woutlo, b0, q);
        if (lq == 0) op[1023] = q[0] + bout;
    }
}

extern "C" void kernel_launch(void* const* d_in, const int* in_sizes, int n_in,
                              void* d_out, int out_size, void* d_ws, size_t ws_size,
                              hipStream_t stream) {
    lstm_ar_kernel<<<dim3(64), dim3(1024), 0, stream>>>(
        (const float*)d_in[0],  (const float*)d_in[1],
        (const float*)d_in[2],  (const float*)d_in[3],
        (const float*)d_in[4],  (const float*)d_in[5],
        (const float*)d_in[6],  (const float*)d_in[7],
        (const float*)d_in[8],  (const float*)d_in[9],
        (const float*)d_in[10], (const float*)d_in[11],
        (float*)d_out);
}